// Round 4
// baseline (129.644 us; speedup 1.0000x reference)
//
#include <hip/hip_runtime.h>
#include <hip/hip_bf16.h>

#define N_SPK 2048
#define M_UTT 10
#define D_DIM 256
#define NM (N_SPK * M_UTT)   // 20480

typedef __attribute__((ext_vector_type(8))) short bf16x8_t;
typedef __attribute__((ext_vector_type(16))) float f32x16_t;

__device__ __forceinline__ short f2bf(float x) {
  __hip_bfloat16 h = __float2bfloat16(x);
  return *reinterpret_cast<short*>(&h);
}

// ---------------- K1: fused prep ----------------
// One block per speaker n (2048 blocks x 256 threads, d = tid):
//  - centroid v = sum_m(e) / max(||sum||, 1e-11)  (== mean/max(||mean||,1e-12))
//  - Bf: centroid in 32x32x16 MFMA A-frag order
//  - per-utterance rn = 1/max(||e_m||,1e-12), dvals = cos(e_m, v)
//  - embn = bf16(e_m * rn)  (row-major [NM][256])
//  - zero rowsum rows, zero out[0]
__global__ __launch_bounds__(256) void k_prep(const float* __restrict__ emb,
                                              __hip_bfloat16* __restrict__ Bf,
                                              __hip_bfloat16* __restrict__ embn,
                                              float* __restrict__ dvals,
                                              float* __restrict__ rowsum,
                                              float* __restrict__ out) {
  const int n = blockIdx.x, d = threadIdx.x;
  const int wid = d >> 6, lane = d & 63;
  const float* p = emb + (size_t)n * (M_UTT * D_DIM) + d;

  float e[M_UTT];
  float s = 0.f;
#pragma unroll
  for (int m = 0; m < M_UTT; ++m) { e[m] = p[m * D_DIM]; s += e[m]; }

  // centroid norm (block reduce of s^2)
  float ss = s * s;
#pragma unroll
  for (int o = 32; o >= 1; o >>= 1) ss += __shfl_xor(ss, o, 64);
  __shared__ float redc[4];
  if (lane == 0) redc[wid] = ss;
  __syncthreads();
  float tot = redc[0] + redc[1] + redc[2] + redc[3];
  float inv = 1.0f / fmaxf(sqrtf(tot), 1e-11f);
  float v = s * inv;

  // Bf fragment layout (verified):
  // Bf[((n>>5)*16 + ks)*64 + lh*32 + (n&31)]*8 + j  holds cent[n][ks*16+lh*8+j]
  int idx = (((n >> 5) * 16 + (d >> 4)) * 64 + ((d >> 3) & 1) * 32 + (n & 31)) * 8 + (d & 7);
  Bf[idx] = __float2bfloat16(v);

  // per-utterance ||e||^2 and e.v (block reduces)
  __shared__ float redm[M_UTT][2][4];
#pragma unroll
  for (int m = 0; m < M_UTT; ++m) {
    float a = e[m] * e[m], bb = e[m] * v;
#pragma unroll
    for (int o = 32; o >= 1; o >>= 1) {
      a += __shfl_xor(a, o, 64);
      bb += __shfl_xor(bb, o, 64);
    }
    if (lane == 0) { redm[m][0][wid] = a; redm[m][1][wid] = bb; }
  }
  __syncthreads();
  __shared__ float rnb[M_UTT];
  if (d < M_UTT) {
    float ssm = redm[d][0][0] + redm[d][0][1] + redm[d][0][2] + redm[d][0][3];
    float dtm = redm[d][1][0] + redm[d][1][1] + redm[d][1][2] + redm[d][1][3];
    float rn = 1.0f / fmaxf(sqrtf(ssm), 1e-12f);
    rnb[d] = rn;
    dvals[n * M_UTT + d] = dtm * rn;   // cos(e_m, centroid_n)
    rowsum[n * M_UTT + d] = 0.f;
  }
  if (n == 0 && d == 0) out[0] = 0.f;
  __syncthreads();

  short* eo = (short*)embn + (size_t)n * (M_UTT * D_DIM) + d;
#pragma unroll
  for (int m = 0; m < M_UTT; ++m) eo[m * D_DIM] = f2bf(e[m] * rnb[m]);
}

// ---------------- K2: fused GEMM + exp row-sums (reg-resident B) ----------------
// Swapped operands: D = cent_frag * emb_frag -> each lane owns emb rows.
// Wave = 64 emb rows x 64 cent cols; B (emb rows, K=256) lives entirely in
// 128 VGPRs, loaded once from L1/L2. K-loop touches ONLY the L2-hot 1MB
// centroid frag array (coalesced 1KB/wave, depth-3 prefetch) + 4 MFMAs/iter.
// No LDS, no barriers. Block = 8 waves (4 row x 2 col) = 256 rows x 128 cols.
// gridDim=(80,16): 80%8==0 -> all 16 col-splits of a row-chunk share an XCD.
__global__ __launch_bounds__(512, 2) void k_gemm(const __hip_bfloat16* __restrict__ embn,
                                                 const __hip_bfloat16* __restrict__ Bf,
                                                 float* __restrict__ rowsum,
                                                 const float* __restrict__ wp) {
  const float aw = fabsf(wp[0]);
  const int tid = threadIdx.x;
  const int lane = tid & 63, w = tid >> 6;
  const int l31 = lane & 31, lh = lane >> 5;
  const int wr = w >> 1, wc = w & 1;
  const int row0 = blockIdx.x * 256 + wr * 64;     // this wave's 64 emb rows
  const int cg0 = blockIdx.y * 4 + wc * 2;         // this wave's 2 cent col-groups

  const bf16x8_t* bp0 = (const bf16x8_t*)Bf + (size_t)(cg0 * 16) * 64 + lane;
  const bf16x8_t* bp1 = (const bf16x8_t*)Bf + (size_t)((cg0 + 1) * 16) * 64 + lane;

  // centroid-frag prefetch ring, depth 3
  bf16x8_t cb0[3], cb1[3];
#pragma unroll
  for (int p = 0; p < 3; ++p) { cb0[p] = bp0[p * 64]; cb1[p] = bp1[p * 64]; }

  // B operand: this wave's 64 rows, full K, in registers (128 VGPR).
  // frag (rg, ks): lane holds embn[row0+rg*32+l31][ks*16 + lh*8 .. +8]
  bf16x8_t breg[2][16];
#pragma unroll
  for (int rg = 0; rg < 2; ++rg) {
    const bf16x8_t* rowp =
        (const bf16x8_t*)embn + (size_t)(row0 + rg * 32 + l31) * 32 + lh;
#pragma unroll
    for (int ks = 0; ks < 16; ++ks) breg[rg][ks] = rowp[ks * 2];
  }

  f32x16_t acc[2][2];
#pragma unroll
  for (int rg = 0; rg < 2; ++rg)
#pragma unroll
    for (int ci = 0; ci < 2; ++ci)
#pragma unroll
      for (int r = 0; r < 16; ++r) acc[rg][ci][r] = 0.f;

#pragma unroll
  for (int ks = 0; ks < 16; ++ks) {
    bf16x8_t b0 = cb0[ks % 3], b1 = cb1[ks % 3];
    if (ks + 3 < 16) {
      cb0[ks % 3] = bp0[(ks + 3) * 64];
      cb1[ks % 3] = bp1[(ks + 3) * 64];
    }
    acc[0][0] = __builtin_amdgcn_mfma_f32_32x32x16_bf16(b0, breg[0][ks], acc[0][0], 0, 0, 0);
    acc[0][1] = __builtin_amdgcn_mfma_f32_32x32x16_bf16(b1, breg[0][ks], acc[0][1], 0, 0, 0);
    acc[1][0] = __builtin_amdgcn_mfma_f32_32x32x16_bf16(b0, breg[1][ks], acc[1][0], 0, 0, 0);
    acc[1][1] = __builtin_amdgcn_mfma_f32_32x32x16_bf16(b1, breg[1][ks], acc[1][1], 0, 0, 0);
  }

  // epilogue: lane holds rows rg*32+l31 vs 32 cents (2 ci x 16 regs);
  // exp-sum in-lane, combine lh halves with one shfl, 2 atomics per lane<32.
#pragma unroll
  for (int rg = 0; rg < 2; ++rg) {
    float s = 0.f;
#pragma unroll
    for (int ci = 0; ci < 2; ++ci)
#pragma unroll
      for (int r = 0; r < 16; ++r)
        s += __expf(fmaf(aw, acc[rg][ci][r], -aw));
    s += __shfl_xor(s, 32, 64);
    if (lane < 32) atomicAdd(&rowsum[row0 + rg * 32 + lane], s);
  }
}

// ---------------- K3: final reduction -> scalar loss ----------------
// out = sum_r [log(rowsum_r) + aw*(1 - dval_r)] / NM   (b cancels)
__global__ __launch_bounds__(256) void k_final(const float* __restrict__ rowsum,
                                               const float* __restrict__ dvals,
                                               const float* __restrict__ wp,
                                               float* __restrict__ out) {
  const float aw = fabsf(wp[0]);
  int base = blockIdx.x * 512 + threadIdx.x;
  float c = 0.f;
#pragma unroll
  for (int j = 0; j < 2; ++j) {
    int r = base + j * 256;
    c += logf(rowsum[r]) + aw * (1.0f - dvals[r]);
  }
#pragma unroll
  for (int o = 32; o >= 1; o >>= 1) c += __shfl_xor(c, o, 64);
  __shared__ float rs[4];
  int wid = threadIdx.x >> 6, lane = threadIdx.x & 63;
  if (lane == 0) rs[wid] = c;
  __syncthreads();
  if (threadIdx.x == 0)
    atomicAdd(out, (rs[0] + rs[1] + rs[2] + rs[3]) * (1.0f / (float)NM));
}

extern "C" void kernel_launch(void* const* d_in, const int* in_sizes, int n_in,
                              void* d_out, int out_size, void* d_ws, size_t ws_size,
                              hipStream_t stream) {
  const float* emb = (const float*)d_in[0];
  const float* wp  = (const float*)d_in[1];
  float* out = (float*)d_out;

  char* ws = (char*)d_ws;
  float* rowsum = (float*)(ws);                            // 80 KB @ 0
  float* dvals  = (float*)(ws + (128 << 10));              // 80 KB @ 128K
  __hip_bfloat16* Bf   = (__hip_bfloat16*)(ws + (1 << 20)); // 1 MB @ 1M (frag order)
  __hip_bfloat16* embn = (__hip_bfloat16*)(ws + (2 << 20)); // 10 MB @ 2M (normalized)

  k_prep<<<N_SPK, 256, 0, stream>>>(emb, Bf, embn, dvals, rowsum, out);
  k_gemm<<<dim3(NM / 256, 16), 512, 0, stream>>>(embn, Bf, rowsum, wp);
  k_final<<<NM / 512, 256, 0, stream>>>(rowsum, dvals, wp, out);
}

// Round 5
// 116.064 us; speedup vs baseline: 1.1170x; 1.1170x over previous
//
#include <hip/hip_runtime.h>
#include <hip/hip_bf16.h>

#define N_SPK 2048
#define M_UTT 10
#define D_DIM 256
#define NM (N_SPK * M_UTT)   // 20480

typedef __attribute__((ext_vector_type(8))) short bf16x8_t;
typedef __attribute__((ext_vector_type(16))) float f32x16_t;

__device__ __forceinline__ short f2bf(float x) {
  __hip_bfloat16 h = __float2bfloat16(x);
  return *reinterpret_cast<short*>(&h);
}

// ---------------- K1: fused prep ----------------
// One block per speaker n (2048 blocks x 256 threads, d = tid):
//  - centroid v = sum_m(e) / max(||sum||, 1e-11)  (== mean/max(||mean||,1e-12))
//  - Bf: centroid in 32x32x16 MFMA A-frag order (verified layout)
//  - embn: normalized rows in the SAME 32x32x16 frag order (B operand):
//      unit u = ((row>>5)*16 + (d>>4))*64 + ((d>>3)&1)*32 + (row&31),
//      embn[u*8 + (d&7)] = bf16(e[row][d] * rn_row)
//  - dvals = cos(e_m, v); zero rowsum, zero out[0]
__global__ __launch_bounds__(256) void k_prep(const float* __restrict__ emb,
                                              __hip_bfloat16* __restrict__ Bf,
                                              __hip_bfloat16* __restrict__ embn,
                                              float* __restrict__ dvals,
                                              float* __restrict__ rowsum,
                                              float* __restrict__ out) {
  const int n = blockIdx.x, d = threadIdx.x;
  const int wid = d >> 6, lane = d & 63;
  const float* p = emb + (size_t)n * (M_UTT * D_DIM) + d;

  float e[M_UTT];
  float s = 0.f;
#pragma unroll
  for (int m = 0; m < M_UTT; ++m) { e[m] = p[m * D_DIM]; s += e[m]; }

  // centroid norm (block reduce of s^2)
  float ss = s * s;
#pragma unroll
  for (int o = 32; o >= 1; o >>= 1) ss += __shfl_xor(ss, o, 64);
  __shared__ float redc[4];
  if (lane == 0) redc[wid] = ss;
  __syncthreads();
  float tot = redc[0] + redc[1] + redc[2] + redc[3];
  float inv = 1.0f / fmaxf(sqrtf(tot), 1e-11f);
  float v = s * inv;

  // Bf fragment layout (verified rounds 2-4)
  int idx = (((n >> 5) * 16 + (d >> 4)) * 64 + ((d >> 3) & 1) * 32 + (n & 31)) * 8 + (d & 7);
  Bf[idx] = __float2bfloat16(v);

  // per-utterance ||e||^2 and e.v (block reduces)
  __shared__ float redm[M_UTT][2][4];
#pragma unroll
  for (int m = 0; m < M_UTT; ++m) {
    float a = e[m] * e[m], bb = e[m] * v;
#pragma unroll
    for (int o = 32; o >= 1; o >>= 1) {
      a += __shfl_xor(a, o, 64);
      bb += __shfl_xor(bb, o, 64);
    }
    if (lane == 0) { redm[m][0][wid] = a; redm[m][1][wid] = bb; }
  }
  __syncthreads();
  __shared__ float rnb[M_UTT];
  if (d < M_UTT) {
    float ssm = redm[d][0][0] + redm[d][0][1] + redm[d][0][2] + redm[d][0][3];
    float dtm = redm[d][1][0] + redm[d][1][1] + redm[d][1][2] + redm[d][1][3];
    float rn = 1.0f / fmaxf(sqrtf(ssm), 1e-12f);
    rnb[d] = rn;
    dvals[n * M_UTT + d] = dtm * rn;   // cos(e_m, centroid_n)
    rowsum[n * M_UTT + d] = 0.f;
  }
  if (n == 0 && d == 0) out[0] = 0.f;
  __syncthreads();

  short* eo = (short*)embn;
#pragma unroll
  for (int m = 0; m < M_UTT; ++m) {
    int row = n * M_UTT + m;
    int u = (((row >> 5) * 16 + (d >> 4)) * 64 + ((d >> 3) & 1) * 32 + (row & 31));
    eo[u * 8 + (d & 7)] = f2bf(e[m] * rnb[m]);
  }
}

// ---------------- K2: fused GEMM + exp row-sums (reg-resident B, coalesced) ----------------
// Swapped operands: D = cent_frag * emb_frag -> each lane owns emb rows.
// Both operand arrays are pre-laid-out in 32x32x16 frag order, so every load
// is a coalesced 1KB wave-load. breg (64 emb rows x K=256) loads ONCE before
// the loop; K-loop touches only the L2/L1-hot Bf stream (depth-3 ring).
// No LDS, no barriers. Block = 8 waves (4 row x 2 col) = 256 rows x 128 cents.
// Grid (16, 80): x = col-split (consecutive blocks share rows -> L2/L3 reuse).
__global__ __launch_bounds__(512, 2) void k_gemm(const __hip_bfloat16* __restrict__ embn,
                                                 const __hip_bfloat16* __restrict__ Bf,
                                                 float* __restrict__ rowsum,
                                                 const float* __restrict__ wp) {
  const float aw = fabsf(wp[0]);
  const int tid = threadIdx.x;
  const int lane = tid & 63, w = tid >> 6;
  const int l31 = lane & 31;
  const int wr = w >> 1, wc = w & 1;
  const int row0 = blockIdx.y * 256 + wr * 64;     // this wave's 64 emb rows
  const int cg0 = blockIdx.x * 4 + wc * 2;         // this wave's 2 cent col-groups
  const int Rb = row0 >> 5;                        // 32-row block index

  const bf16x8_t* bp0 = (const bf16x8_t*)Bf + (size_t)(cg0 * 16) * 64 + lane;
  const bf16x8_t* bp1 = (const bf16x8_t*)Bf + (size_t)((cg0 + 1) * 16) * 64 + lane;
  const bf16x8_t* fp = (const bf16x8_t*)embn;

  // centroid-frag prefetch ring, depth 3
  bf16x8_t cb0[3], cb1[3];
#pragma unroll
  for (int p = 0; p < 3; ++p) { cb0[p] = bp0[p * 64]; cb1[p] = bp1[p * 64]; }

  // B operand: this wave's 64 rows, full K, in registers — coalesced frag loads.
  bf16x8_t breg[2][16];
#pragma unroll
  for (int rg = 0; rg < 2; ++rg)
#pragma unroll
    for (int ks = 0; ks < 16; ++ks)
      breg[rg][ks] = fp[(size_t)((Rb + rg) * 16 + ks) * 64 + lane];

  f32x16_t acc[2][2];
#pragma unroll
  for (int rg = 0; rg < 2; ++rg)
#pragma unroll
    for (int ci = 0; ci < 2; ++ci)
#pragma unroll
      for (int r = 0; r < 16; ++r) acc[rg][ci][r] = 0.f;

#pragma unroll
  for (int ks = 0; ks < 16; ++ks) {
    bf16x8_t b0 = cb0[ks % 3], b1 = cb1[ks % 3];
    if (ks + 3 < 16) {
      cb0[ks % 3] = bp0[(ks + 3) * 64];
      cb1[ks % 3] = bp1[(ks + 3) * 64];
    }
    acc[0][0] = __builtin_amdgcn_mfma_f32_32x32x16_bf16(b0, breg[0][ks], acc[0][0], 0, 0, 0);
    acc[0][1] = __builtin_amdgcn_mfma_f32_32x32x16_bf16(b1, breg[0][ks], acc[0][1], 0, 0, 0);
    acc[1][0] = __builtin_amdgcn_mfma_f32_32x32x16_bf16(b0, breg[1][ks], acc[1][0], 0, 0, 0);
    acc[1][1] = __builtin_amdgcn_mfma_f32_32x32x16_bf16(b1, breg[1][ks], acc[1][1], 0, 0, 0);
  }

  // epilogue: lane holds rows rg*32+l31 vs 64 cents (2 ci x 16 regs + lh half);
  // exp-sum in-lane, combine halves with one shfl, atomics from lanes<32.
#pragma unroll
  for (int rg = 0; rg < 2; ++rg) {
    float s = 0.f;
#pragma unroll
    for (int ci = 0; ci < 2; ++ci)
#pragma unroll
      for (int r = 0; r < 16; ++r)
        s += __expf(fmaf(aw, acc[rg][ci][r], -aw));
    s += __shfl_xor(s, 32, 64);
    if (lane < 32) atomicAdd(&rowsum[row0 + rg * 32 + lane], s);
  }
}

// ---------------- K3: final reduction -> scalar loss ----------------
// out = sum_r [log(rowsum_r) + aw*(1 - dval_r)] / NM   (b cancels)
__global__ __launch_bounds__(256) void k_final(const float* __restrict__ rowsum,
                                               const float* __restrict__ dvals,
                                               const float* __restrict__ wp,
                                               float* __restrict__ out) {
  const float aw = fabsf(wp[0]);
  int base = blockIdx.x * 512 + threadIdx.x;
  float c = 0.f;
#pragma unroll
  for (int j = 0; j < 2; ++j) {
    int r = base + j * 256;
    c += logf(rowsum[r]) + aw * (1.0f - dvals[r]);
  }
#pragma unroll
  for (int o = 32; o >= 1; o >>= 1) c += __shfl_xor(c, o, 64);
  __shared__ float rs[4];
  int wid = threadIdx.x >> 6, lane = threadIdx.x & 63;
  if (lane == 0) rs[wid] = c;
  __syncthreads();
  if (threadIdx.x == 0)
    atomicAdd(out, (rs[0] + rs[1] + rs[2] + rs[3]) * (1.0f / (float)NM));
}

extern "C" void kernel_launch(void* const* d_in, const int* in_sizes, int n_in,
                              void* d_out, int out_size, void* d_ws, size_t ws_size,
                              hipStream_t stream) {
  const float* emb = (const float*)d_in[0];
  const float* wp  = (const float*)d_in[1];
  float* out = (float*)d_out;

  char* ws = (char*)d_ws;
  float* rowsum = (float*)(ws);                            // 80 KB @ 0
  float* dvals  = (float*)(ws + (128 << 10));              // 80 KB @ 128K
  __hip_bfloat16* Bf   = (__hip_bfloat16*)(ws + (1 << 20)); // 1 MB @ 1M (frag order)
  __hip_bfloat16* embn = (__hip_bfloat16*)(ws + (2 << 20)); // 10 MB @ 2M (frag order)

  k_prep<<<N_SPK, 256, 0, stream>>>(emb, Bf, embn, dvals, rowsum, out);
  k_gemm<<<dim3(16, NM / 256), 512, 0, stream>>>(embn, Bf, rowsum, wp);
  k_final<<<NM / 512, 256, 0, stream>>>(rowsum, dvals, wp, out);
}

// Round 6
// 108.038 us; speedup vs baseline: 1.2000x; 1.0743x over previous
//
#include <hip/hip_runtime.h>
#include <hip/hip_bf16.h>

#define N_SPK 2048
#define M_UTT 10
#define D_DIM 256
#define NM (N_SPK * M_UTT)   // 20480

typedef __attribute__((ext_vector_type(8))) short bf16x8_t;
typedef __attribute__((ext_vector_type(16))) float f32x16_t;

__device__ __forceinline__ short f2bf(float x) {
  __hip_bfloat16 h = __float2bfloat16(x);
  return *reinterpret_cast<short*>(&h);
}

// ---------------- K1: fused prep ----------------
// One block per speaker n (2048 blocks x 256 threads, d = tid):
//  - centroid v = sum_m(e) / max(||sum||, 1e-11)  (== mean/max(||mean||,1e-12))
//  - Bf: centroid in 32x32x16 MFMA A-frag order (verified layout)
//  - embn: normalized rows in the SAME 32x32x16 frag order (B operand)
//  - dvals = cos(e_m, v); zero rowsum, zero out[0]
__global__ __launch_bounds__(256) void k_prep(const float* __restrict__ emb,
                                              __hip_bfloat16* __restrict__ Bf,
                                              __hip_bfloat16* __restrict__ embn,
                                              float* __restrict__ dvals,
                                              float* __restrict__ rowsum,
                                              float* __restrict__ out) {
  const int n = blockIdx.x, d = threadIdx.x;
  const int wid = d >> 6, lane = d & 63;
  const float* p = emb + (size_t)n * (M_UTT * D_DIM) + d;

  float e[M_UTT];
  float s = 0.f;
#pragma unroll
  for (int m = 0; m < M_UTT; ++m) { e[m] = p[m * D_DIM]; s += e[m]; }

  // centroid norm (block reduce of s^2)
  float ss = s * s;
#pragma unroll
  for (int o = 32; o >= 1; o >>= 1) ss += __shfl_xor(ss, o, 64);
  __shared__ float redc[4];
  if (lane == 0) redc[wid] = ss;
  __syncthreads();
  float tot = redc[0] + redc[1] + redc[2] + redc[3];
  float inv = 1.0f / fmaxf(sqrtf(tot), 1e-11f);
  float v = s * inv;

  // Bf fragment layout (verified rounds 2-5)
  int idx = (((n >> 5) * 16 + (d >> 4)) * 64 + ((d >> 3) & 1) * 32 + (n & 31)) * 8 + (d & 7);
  Bf[idx] = __float2bfloat16(v);

  // per-utterance ||e||^2 and e.v (block reduces)
  __shared__ float redm[M_UTT][2][4];
#pragma unroll
  for (int m = 0; m < M_UTT; ++m) {
    float a = e[m] * e[m], bb = e[m] * v;
#pragma unroll
    for (int o = 32; o >= 1; o >>= 1) {
      a += __shfl_xor(a, o, 64);
      bb += __shfl_xor(bb, o, 64);
    }
    if (lane == 0) { redm[m][0][wid] = a; redm[m][1][wid] = bb; }
  }
  __syncthreads();
  __shared__ float rnb[M_UTT];
  if (d < M_UTT) {
    float ssm = redm[d][0][0] + redm[d][0][1] + redm[d][0][2] + redm[d][0][3];
    float dtm = redm[d][1][0] + redm[d][1][1] + redm[d][1][2] + redm[d][1][3];
    float rn = 1.0f / fmaxf(sqrtf(ssm), 1e-12f);
    rnb[d] = rn;
    dvals[n * M_UTT + d] = dtm * rn;   // cos(e_m, centroid_n)
    rowsum[n * M_UTT + d] = 0.f;
  }
  if (n == 0 && d == 0) out[0] = 0.f;
  __syncthreads();

  short* eo = (short*)embn;
#pragma unroll
  for (int m = 0; m < M_UTT; ++m) {
    int row = n * M_UTT + m;
    int u = (((row >> 5) * 16 + (d >> 4)) * 64 + ((d >> 3) & 1) * 32 + (row & 31));
    eo[u * 8 + (d & 7)] = f2bf(e[m] * rnb[m]);
  }
}

// ---------------- K2: fused GEMM + exp row-sums ----------------
// Block = 4 waves = 256 emb rows x 128 cent cols.
//  - centroid frags for the block's 128 cols (64 KB, frag-order = linear)
//    staged ONCE into LDS via global_load_lds; all 4 waves stream them via
//    contiguous conflict-free ds_read_b128. Zero global traffic in K-loop.
//  - each wave's 64 emb rows (breg[2][16], 128 VGPR) load once, coalesced,
//    and are REUSED across 2 col-chunks -> compiler must keep them resident.
//  - per chunk: 16 K-iters x 4 MFMA; exp-epilogue accumulates into rowacc;
//    one shfl + 2 atomics per lane<32 at the very end.
__global__ __launch_bounds__(256, 2) void k_gemm(const __hip_bfloat16* __restrict__ embn,
                                                 const __hip_bfloat16* __restrict__ Bf,
                                                 float* __restrict__ rowsum,
                                                 const float* __restrict__ wp) {
  __shared__ short Bs[128 * 256];  // 64 KB: 4 col-groups x 16 ks x 64 units x 8
  const float aw = fabsf(wp[0]);
  const int tid = threadIdx.x;
  const int lane = tid & 63, w = tid >> 6;
  const int l31 = lane & 31;
  const int row0 = blockIdx.y * 256 + w * 64;   // this wave's 64 emb rows
  const int Rb = blockIdx.y * 8 + w * 2;        // 32-row block index

  // ---- stage this block's 128 centroid cols into LDS (linear copy) ----
  {
    const short* src = (const short*)Bf + (size_t)blockIdx.x * 32768 + w * 512 + lane * 8;
#pragma unroll
    for (int it = 0; it < 16; ++it) {
      __builtin_amdgcn_global_load_lds(
          (const __attribute__((address_space(1))) void*)(src + it * 2048),
          (__attribute__((address_space(3))) void*)&Bs[it * 2048 + w * 512],
          16, 0, 0);
    }
  }

  // ---- breg: this wave's 64 rows, full K, in registers (coalesced, once) ----
  const bf16x8_t* fp = (const bf16x8_t*)embn;
  bf16x8_t breg[2][16];
#pragma unroll
  for (int rg = 0; rg < 2; ++rg)
#pragma unroll
    for (int ks = 0; ks < 16; ++ks)
      breg[rg][ks] = fp[(size_t)((Rb + rg) * 16 + ks) * 64 + lane];

  asm volatile("s_waitcnt vmcnt(0)" ::: "memory");
  __syncthreads();

  float rowacc[2] = {0.f, 0.f};

#pragma unroll
  for (int c = 0; c < 2; ++c) {
    f32x16_t acc[2][2];
#pragma unroll
    for (int rg = 0; rg < 2; ++rg)
#pragma unroll
      for (int ci = 0; ci < 2; ++ci)
#pragma unroll
        for (int r = 0; r < 16; ++r) acc[rg][ci][r] = 0.f;

#pragma unroll
    for (int ks = 0; ks < 16; ++ks) {
      bf16x8_t c0 = *(const bf16x8_t*)&Bs[((2 * c) * 16 + ks) * 512 + lane * 8];
      bf16x8_t c1 = *(const bf16x8_t*)&Bs[((2 * c + 1) * 16 + ks) * 512 + lane * 8];
      acc[0][0] = __builtin_amdgcn_mfma_f32_32x32x16_bf16(c0, breg[0][ks], acc[0][0], 0, 0, 0);
      acc[0][1] = __builtin_amdgcn_mfma_f32_32x32x16_bf16(c1, breg[0][ks], acc[0][1], 0, 0, 0);
      acc[1][0] = __builtin_amdgcn_mfma_f32_32x32x16_bf16(c0, breg[1][ks], acc[1][0], 0, 0, 0);
      acc[1][1] = __builtin_amdgcn_mfma_f32_32x32x16_bf16(c1, breg[1][ks], acc[1][1], 0, 0, 0);
    }

    // exp-epilogue for this chunk's 64 cols (lane-local rows)
#pragma unroll
    for (int rg = 0; rg < 2; ++rg) {
      float s = 0.f;
#pragma unroll
      for (int ci = 0; ci < 2; ++ci)
#pragma unroll
        for (int r = 0; r < 16; ++r)
          s += __expf(fmaf(aw, acc[rg][ci][r], -aw));
      rowacc[rg] += s;
    }
  }

  // combine lh halves, one atomic per row
#pragma unroll
  for (int rg = 0; rg < 2; ++rg) {
    float s = rowacc[rg] + __shfl_xor(rowacc[rg], 32, 64);
    if (lane < 32) atomicAdd(&rowsum[row0 + rg * 32 + lane], s);
  }
}

// ---------------- K3: final reduction -> scalar loss ----------------
// out = sum_r [log(rowsum_r) + aw*(1 - dval_r)] / NM   (b cancels)
__global__ __launch_bounds__(256) void k_final(const float* __restrict__ rowsum,
                                               const float* __restrict__ dvals,
                                               const float* __restrict__ wp,
                                               float* __restrict__ out) {
  const float aw = fabsf(wp[0]);
  int base = blockIdx.x * 512 + threadIdx.x;
  float c = 0.f;
#pragma unroll
  for (int j = 0; j < 2; ++j) {
    int r = base + j * 256;
    c += logf(rowsum[r]) + aw * (1.0f - dvals[r]);
  }
#pragma unroll
  for (int o = 32; o >= 1; o >>= 1) c += __shfl_xor(c, o, 64);
  __shared__ float rs[4];
  int wid = threadIdx.x >> 6, lane = threadIdx.x & 63;
  if (lane == 0) rs[wid] = c;
  __syncthreads();
  if (threadIdx.x == 0)
    atomicAdd(out, (rs[0] + rs[1] + rs[2] + rs[3]) * (1.0f / (float)NM));
}

extern "C" void kernel_launch(void* const* d_in, const int* in_sizes, int n_in,
                              void* d_out, int out_size, void* d_ws, size_t ws_size,
                              hipStream_t stream) {
  const float* emb = (const float*)d_in[0];
  const float* wp  = (const float*)d_in[1];
  float* out = (float*)d_out;

  char* ws = (char*)d_ws;
  float* rowsum = (float*)(ws);                            // 80 KB @ 0
  float* dvals  = (float*)(ws + (128 << 10));              // 80 KB @ 128K
  __hip_bfloat16* Bf   = (__hip_bfloat16*)(ws + (1 << 20)); // 1 MB @ 1M (frag order)
  __hip_bfloat16* embn = (__hip_bfloat16*)(ws + (2 << 20)); // 10 MB @ 2M (frag order)

  k_prep<<<N_SPK, 256, 0, stream>>>(emb, Bf, embn, dvals, rowsum, out);
  k_gemm<<<dim3(16, NM / 256), 256, 0, stream>>>(embn, Bf, rowsum, wp);
  k_final<<<NM / 512, 256, 0, stream>>>(rowsum, dvals, wp, out);
}

// Round 7
// 104.940 us; speedup vs baseline: 1.2354x; 1.0295x over previous
//
#include <hip/hip_runtime.h>
#include <hip/hip_bf16.h>

#define N_SPK 2048
#define M_UTT 10
#define D_DIM 256
#define NM (N_SPK * M_UTT)   // 20480

typedef __attribute__((ext_vector_type(8))) short bf16x8_t;
typedef __attribute__((ext_vector_type(16))) float f32x16_t;

__device__ __forceinline__ short f2bf(float x) {
  __hip_bfloat16 h = __float2bfloat16(x);
  return *reinterpret_cast<short*>(&h);
}

// ---------------- K1: fused prep ----------------
// One block per speaker n (2048 blocks x 256 threads, d = tid):
//  - centroid v = sum_m(e) / max(||sum||, 1e-11)  (== mean/max(||mean||,1e-12))
//  - Bf: centroid in 32x32x16 MFMA A-frag order (verified layout)
//  - embn: normalized rows in the SAME 32x32x16 frag order (B operand)
//  - dvals = cos(e_m, v); zero rowsum, zero out[0]
__global__ __launch_bounds__(256) void k_prep(const float* __restrict__ emb,
                                              __hip_bfloat16* __restrict__ Bf,
                                              __hip_bfloat16* __restrict__ embn,
                                              float* __restrict__ dvals,
                                              float* __restrict__ rowsum,
                                              float* __restrict__ out) {
  const int n = blockIdx.x, d = threadIdx.x;
  const int wid = d >> 6, lane = d & 63;
  const float* p = emb + (size_t)n * (M_UTT * D_DIM) + d;

  float e[M_UTT];
  float s = 0.f;
#pragma unroll
  for (int m = 0; m < M_UTT; ++m) { e[m] = p[m * D_DIM]; s += e[m]; }

  // centroid norm (block reduce of s^2)
  float ss = s * s;
#pragma unroll
  for (int o = 32; o >= 1; o >>= 1) ss += __shfl_xor(ss, o, 64);
  __shared__ float redc[4];
  if (lane == 0) redc[wid] = ss;
  __syncthreads();
  float tot = redc[0] + redc[1] + redc[2] + redc[3];
  float inv = 1.0f / fmaxf(sqrtf(tot), 1e-11f);
  float v = s * inv;

  // Bf fragment layout (verified rounds 2-6)
  int idx = (((n >> 5) * 16 + (d >> 4)) * 64 + ((d >> 3) & 1) * 32 + (n & 31)) * 8 + (d & 7);
  Bf[idx] = __float2bfloat16(v);

  // per-utterance ||e||^2 and e.v (block reduces)
  __shared__ float redm[M_UTT][2][4];
#pragma unroll
  for (int m = 0; m < M_UTT; ++m) {
    float a = e[m] * e[m], bb = e[m] * v;
#pragma unroll
    for (int o = 32; o >= 1; o >>= 1) {
      a += __shfl_xor(a, o, 64);
      bb += __shfl_xor(bb, o, 64);
    }
    if (lane == 0) { redm[m][0][wid] = a; redm[m][1][wid] = bb; }
  }
  __syncthreads();
  __shared__ float rnb[M_UTT];
  if (d < M_UTT) {
    float ssm = redm[d][0][0] + redm[d][0][1] + redm[d][0][2] + redm[d][0][3];
    float dtm = redm[d][1][0] + redm[d][1][1] + redm[d][1][2] + redm[d][1][3];
    float rn = 1.0f / fmaxf(sqrtf(ssm), 1e-12f);
    rnb[d] = rn;
    dvals[n * M_UTT + d] = dtm * rn;   // cos(e_m, centroid_n)
    rowsum[n * M_UTT + d] = 0.f;
  }
  if (n == 0 && d == 0) out[0] = 0.f;
  __syncthreads();

  short* eo = (short*)embn;
#pragma unroll
  for (int m = 0; m < M_UTT; ++m) {
    int row = n * M_UTT + m;
    int u = (((row >> 5) * 16 + (d >> 4)) * 64 + ((d >> 3) & 1) * 32 + (row & 31));
    eo[u * 8 + (d & 7)] = f2bf(e[m] * rnb[m]);
  }
}

// ---------------- K2: fused GEMM + exp row-sums ----------------
// Block = 4 waves = 256 emb rows x 128 cent cols (identical math to round 6).
// NEW: bijective XCD-aware remap of the 1280 blocks. lid%8 = XCD
// (round-robin dispatch); each XCD owns the 10 row-groups r==xcd (mod 8) and
// runs the 16 col-splits of one row-group on consecutive slots, so its embn
// chunks (<=4 live x 128KB) + the 1MB Bf stream stay L2-resident per XCD.
// L3 traffic: 240 MB -> ~18 MB.
__global__ __launch_bounds__(256, 2) void k_gemm(const __hip_bfloat16* __restrict__ embn,
                                                 const __hip_bfloat16* __restrict__ Bf,
                                                 float* __restrict__ rowsum,
                                                 const float* __restrict__ wp) {
  __shared__ short Bs[128 * 256];  // 64 KB: 4 col-groups x 16 ks x 64 units x 8
  const float aw = fabsf(wp[0]);
  const int tid = threadIdx.x;
  const int lane = tid & 63, w = tid >> 6;

  const int lid = blockIdx.x + 16 * blockIdx.y;  // 0..1279
  const int xcd = lid & 7;
  const int slot = lid >> 3;                     // 0..159
  const int colsplit = slot & 15;                // inner: col-splits back-to-back
  const int rowg = xcd + 8 * (slot >> 4);        // 0..79, rowg == xcd (mod 8)

  const int row0 = rowg * 256 + w * 64;          // this wave's 64 emb rows
  const int Rb = rowg * 8 + w * 2;               // 32-row block index

  // ---- stage this block's 128 centroid cols into LDS (linear copy) ----
  {
    const short* src = (const short*)Bf + (size_t)colsplit * 32768 + w * 512 + lane * 8;
#pragma unroll
    for (int it = 0; it < 16; ++it) {
      __builtin_amdgcn_global_load_lds(
          (const __attribute__((address_space(1))) void*)(src + it * 2048),
          (__attribute__((address_space(3))) void*)&Bs[it * 2048 + w * 512],
          16, 0, 0);
    }
  }

  // ---- breg: this wave's 64 rows, full K, in registers (coalesced, once) ----
  const bf16x8_t* fp = (const bf16x8_t*)embn;
  bf16x8_t breg[2][16];
#pragma unroll
  for (int rg = 0; rg < 2; ++rg)
#pragma unroll
    for (int ks = 0; ks < 16; ++ks)
      breg[rg][ks] = fp[(size_t)((Rb + rg) * 16 + ks) * 64 + lane];

  asm volatile("s_waitcnt vmcnt(0)" ::: "memory");
  __syncthreads();

  float rowacc[2] = {0.f, 0.f};

#pragma unroll
  for (int c = 0; c < 2; ++c) {
    f32x16_t acc[2][2];
#pragma unroll
    for (int rg = 0; rg < 2; ++rg)
#pragma unroll
      for (int ci = 0; ci < 2; ++ci)
#pragma unroll
        for (int r = 0; r < 16; ++r) acc[rg][ci][r] = 0.f;

#pragma unroll
    for (int ks = 0; ks < 16; ++ks) {
      bf16x8_t c0 = *(const bf16x8_t*)&Bs[((2 * c) * 16 + ks) * 512 + lane * 8];
      bf16x8_t c1 = *(const bf16x8_t*)&Bs[((2 * c + 1) * 16 + ks) * 512 + lane * 8];
      acc[0][0] = __builtin_amdgcn_mfma_f32_32x32x16_bf16(c0, breg[0][ks], acc[0][0], 0, 0, 0);
      acc[0][1] = __builtin_amdgcn_mfma_f32_32x32x16_bf16(c1, breg[0][ks], acc[0][1], 0, 0, 0);
      acc[1][0] = __builtin_amdgcn_mfma_f32_32x32x16_bf16(c0, breg[1][ks], acc[1][0], 0, 0, 0);
      acc[1][1] = __builtin_amdgcn_mfma_f32_32x32x16_bf16(c1, breg[1][ks], acc[1][1], 0, 0, 0);
    }

    // exp-epilogue for this chunk's 64 cols (lane-local rows)
#pragma unroll
    for (int rg = 0; rg < 2; ++rg) {
      float s = 0.f;
#pragma unroll
      for (int ci = 0; ci < 2; ++ci)
#pragma unroll
        for (int r = 0; r < 16; ++r)
          s += __expf(fmaf(aw, acc[rg][ci][r], -aw));
      rowacc[rg] += s;
    }
  }

  // combine lh halves, one atomic per row
#pragma unroll
  for (int rg = 0; rg < 2; ++rg) {
    float s = rowacc[rg] + __shfl_xor(rowacc[rg], 32, 64);
    if (lane < 32) atomicAdd(&rowsum[row0 + rg * 32 + lane], s);
  }
}

// ---------------- K3: final reduction -> scalar loss ----------------
// out = sum_r [log(rowsum_r) + aw*(1 - dval_r)] / NM   (b cancels)
__global__ __launch_bounds__(256) void k_final(const float* __restrict__ rowsum,
                                               const float* __restrict__ dvals,
                                               const float* __restrict__ wp,
                                               float* __restrict__ out) {
  const float aw = fabsf(wp[0]);
  int base = blockIdx.x * 512 + threadIdx.x;
  float c = 0.f;
#pragma unroll
  for (int j = 0; j < 2; ++j) {
    int r = base + j * 256;
    c += logf(rowsum[r]) + aw * (1.0f - dvals[r]);
  }
#pragma unroll
  for (int o = 32; o >= 1; o >>= 1) c += __shfl_xor(c, o, 64);
  __shared__ float rs[4];
  int wid = threadIdx.x >> 6, lane = threadIdx.x & 63;
  if (lane == 0) rs[wid] = c;
  __syncthreads();
  if (threadIdx.x == 0)
    atomicAdd(out, (rs[0] + rs[1] + rs[2] + rs[3]) * (1.0f / (float)NM));
}

extern "C" void kernel_launch(void* const* d_in, const int* in_sizes, int n_in,
                              void* d_out, int out_size, void* d_ws, size_t ws_size,
                              hipStream_t stream) {
  const float* emb = (const float*)d_in[0];
  const float* wp  = (const float*)d_in[1];
  float* out = (float*)d_out;

  char* ws = (char*)d_ws;
  float* rowsum = (float*)(ws);                            // 80 KB @ 0
  float* dvals  = (float*)(ws + (128 << 10));              // 80 KB @ 128K
  __hip_bfloat16* Bf   = (__hip_bfloat16*)(ws + (1 << 20)); // 1 MB @ 1M (frag order)
  __hip_bfloat16* embn = (__hip_bfloat16*)(ws + (2 << 20)); // 10 MB @ 2M (frag order)

  k_prep<<<N_SPK, 256, 0, stream>>>(emb, Bf, embn, dvals, rowsum, out);
  k_gemm<<<dim3(16, NM / 256), 256, 0, stream>>>(embn, Bf, rowsum, wp);
  k_final<<<NM / 512, 256, 0, stream>>>(rowsum, dvals, wp, out);
}